// Round 7
// baseline (214.134 us; speedup 1.0000x reference)
//
#include <hip/hip_runtime.h>

#define POOLED 7
#define SCALE  0.25f
#define CCH    256
#define HH     128
#define WW     128
#define HW     (HH * WW)

#define NCH      16                    // channels per chunk
#define NCHUNK   2                     // chunks per block -> 32 channels/block
#define NBLK_PER_BOX (CCH / (NCH * NCHUNK))  // 8 blocks per box
#define PATCH_H  15                    // row span <= 15 (13/14*roi_h + 2)
#define PATCH_W  16
#define PIXROW   17                    // pixel-index row stride
#define NPIX     (14 * PIXROW + 16)    // 254 pixel slots
#define CHPAD    20                    // dwords per pixel: 16 ch + 4 pad (2-way-free staging)
#define MAXE     12                    // merged entries/bin: max distinct corners = 9 (3x3)

struct BoxMeta { int b, ylo, xlo, h_p, mmax, pad0, pad1, pad2; };  // 32 B

// ---------------- Kernel 1: per-(box, bin) merged weight table ----------------
// grid K x 64 threads (1 wave). Thread p in [0,49) builds the merged
// (lds_offset, weight*sc) list for output bin p of box k. Corner pixels shared
// between the <=4 samples are merged (sum of weights) -> <=9 entries.
__global__ __launch_bounds__(64) void roi_prep(
    const float* __restrict__ boxes, int K,
    BoxMeta* __restrict__ meta, int2* __restrict__ ent)
{
    int k = blockIdx.x;
    if (k >= K) return;
    int p = threadIdx.x;               // 0..63

    const float* box = boxes + (size_t)k * 5;
    int   b  = (int)box[0];
    float x1 = box[1] * SCALE;
    float y1 = box[2] * SCALE;
    float x2 = box[3] * SCALE;
    float y2 = box[4] * SCALE;

    float roi_w = fmaxf(x2 - x1, 1.0f);
    float roi_h = fmaxf(y2 - y1, 1.0f);
    float bin_w = roi_w * (1.0f / POOLED);
    float bin_h = roi_h * (1.0f / POOLED);
    int gw = (int)ceilf(roi_w * (1.0f / POOLED));
    int gh = (int)ceilf(roi_h * (1.0f / POOLED));
    float inv_gh = 1.0f / (float)gh;
    float inv_gw = 1.0f / (float)gw;
    int ns = gh * gw;
    float sc = inv_gh * inv_gw;

    // patch bounds (identical expressions to the verified R3-R5 kernels)
    float ymin = y1 + 0.5f * bin_h * inv_gh;
    float ymax = y1 + 6 * bin_h + ((gh - 1) + 0.5f) * bin_h * inv_gh;
    float xmin = x1 + 0.5f * bin_w * inv_gw;

    int ylo = min((int)fmaxf(ymin, 0.0f), HH - 1);
    int xlo = min((int)fmaxf(xmin, 0.0f), WW - 1);
    int ylmax = min((int)fmaxf(ymax, 0.0f), HH - 1);
    int h_p = min(ylmax + 1, HH - 1) - ylo + 1;
    if (h_p > PATCH_H) h_p = PATCH_H;

    int pc = min(p, 48);
    int pw = pc % POOLED;
    int ph = pc / POOLED;

    int   offs[MAXE];
    float ws[MAXE];
    int m = 0;

    for (int s = 0; s < ns; ++s) {
        int iy = s % gh;
        int ix = s / gh;

        float y = y1 + ph * bin_h + (iy + 0.5f) * bin_h * inv_gh;
        float x = x1 + pw * bin_w + (ix + 0.5f) * bin_w * inv_gw;
        bool valid = (y >= -1.0f) && (y <= (float)HH) && (x >= -1.0f) && (x <= (float)WW);

        float yc = fmaxf(y, 0.0f);
        int yl = min((int)yc, HH - 1);
        int yh2 = min(yl + 1, HH - 1);
        float ly = (yl >= HH - 1) ? 0.0f : (yc - (float)yl);
        float hy = 1.0f - ly;

        float xc = fmaxf(x, 0.0f);
        int xl = min((int)xc, WW - 1);
        int xh2 = min(xl + 1, WW - 1);
        float lx = (xl >= WW - 1) ? 0.0f : (xc - (float)xl);
        float hx = 1.0f - lx;

        float mk = valid ? 1.0f : 0.0f;

        int ry  = max(0, min(yl  - ylo, h_p - 1));
        int ryh = max(0, min(yh2 - ylo, h_p - 1));
        int rxl = max(0, min(xl  - xlo, PATCH_W - 1));
        int rxh = max(0, min(xh2 - xlo, PATCH_W - 1));

        int   co[4] = { (ry  * PIXROW + rxl) * CHPAD, (ry  * PIXROW + rxh) * CHPAD,
                        (ryh * PIXROW + rxl) * CHPAD, (ryh * PIXROW + rxh) * CHPAD };
        float cw[4] = { hy * hx * mk, hy * lx * mk, ly * hx * mk, ly * lx * mk };

        for (int c = 0; c < 4; ++c) {
            int o = co[c];
            float w = cw[c];
            bool found = false;
            for (int j = 0; j < m; ++j) {
                if (offs[j] == o) { ws[j] += w; found = true; break; }
            }
            if (!found && m < MAXE) { offs[m] = o; ws[m] = w; ++m; }
        }
    }

    if (p >= 49) m = 0;
    for (int j = 0; j < m; ++j) ws[j] *= sc;
    for (int j = m; j < MAXE; ++j) { offs[j] = 0; ws[j] = 0.0f; }

    // wave-wide max of m
    int mm = m;
    for (int d = 1; d < 64; d <<= 1) mm = max(mm, __shfl_xor(mm, d));

    if (p == 0) {
        BoxMeta mt; mt.b = b; mt.ylo = ylo; mt.xlo = xlo; mt.h_p = h_p;
        mt.mmax = mm; mt.pad0 = mt.pad1 = mt.pad2 = 0;
        meta[k] = mt;
    }

    // entries: [k][j][p] so kernel-2 lane loads coalesce (p contiguous)
    int2* eb = ent + (size_t)k * MAXE * 64 + p;
    for (int j = 0; j < MAXE; ++j)
        eb[j * 64] = make_int2(offs[j], __float_as_int(ws[j]));
}

// ---------------- Kernel 2: stage + gather (R5 verified structure) ----------------
__global__ __launch_bounds__(256) void roi_gather(
    const float* __restrict__ feat,
    const BoxMeta* __restrict__ meta,
    const int2* __restrict__ ent,
    float* __restrict__ out, int K)
{
    __shared__ float patch[NPIX * CHPAD];   // 20320 B

    int bx = blockIdx.x;
    int k  = bx >> 3;
    int cb = (bx & 7) * (NCH * NCHUNK);     // channel base: 0..224 step 32
    if (k >= K) return;
    int t = threadIdx.x;
    int p  = t & 63;
    int c4 = t >> 6;                        // wave id = 4-channel slot

    BoxMeta mt = meta[k];                   // k uniform -> scalar loads
    int mmax = mt.mmax;

    // load merged entries into registers (coalesced; shared across chunks)
    int2 e[MAXE];
    const int2* eb = ent + (size_t)k * MAXE * 64 + p;
#pragma unroll
    for (int j = 0; j < MAXE; ++j) {
        if (j >= mmax) break;               // wave-uniform
        e[j] = eb[j * 64];
    }

    // staging mapping: lch = channel-in-chunk, lcol = patch col
    int lch  = t >> 4;                      // 0..15
    int lcol = t & 15;                      // 0..15
    int xcol = min(mt.xlo + lcol, WW - 1);
    int h_p  = mt.h_p;

    for (int ch = 0; ch < NCHUNK; ++ch) {
        if (ch) __syncthreads();            // WAR before overwrite

        {
            const float* g = feat + ((size_t)mt.b * CCH + cb + ch * NCH + lch) * HW + xcol;
            float* lp = patch + lcol * CHPAD + lch;
            for (int r = 0; r < h_p; ++r)
                lp[r * (PIXROW * CHPAD)] = g[(mt.ylo + r) * WW];
        }
        __syncthreads();

        if (p < 49) {
            float4 acc = {0.0f, 0.0f, 0.0f, 0.0f};
            const float* cp = patch + c4 * 4;
#pragma unroll
            for (int j = 0; j < MAXE; ++j) {
                if (j >= mmax) break;       // wave-uniform
                float4 v = *(const float4*)(cp + e[j].x);
                float w = __int_as_float(e[j].y);
                acc.x += w * v.x;
                acc.y += w * v.y;
                acc.z += w * v.z;
                acc.w += w * v.w;
            }
            float* obase = out + ((size_t)k * CCH + cb + ch * NCH + c4 * 4) * 49 + p;
            obase[0]      = acc.x;
            obase[49]     = acc.y;
            obase[2 * 49] = acc.z;
            obase[3 * 49] = acc.w;
        }
    }
}

extern "C" void kernel_launch(void* const* d_in, const int* in_sizes, int n_in,
                              void* d_out, int out_size, void* d_ws, size_t ws_size,
                              hipStream_t stream) {
    const float* feat  = (const float*)d_in[0];
    const float* boxes = (const float*)d_in[1];
    float* out = (float*)d_out;

    int K = in_sizes[1] / 5;

    // workspace layout: meta (32 B/box, 256B-aligned region) then entry table
    size_t meta_bytes = ((size_t)K * sizeof(BoxMeta) + 255) & ~(size_t)255;
    BoxMeta* meta = (BoxMeta*)d_ws;
    int2* ent = (int2*)((char*)d_ws + meta_bytes);
    // table: K * MAXE * 64 * 8 B = 6.1 MB for K=1000 (+ meta) — fits d_ws

    roi_prep<<<K, 64, 0, stream>>>(boxes, K, meta, ent);
    roi_gather<<<K * NBLK_PER_BOX, 256, 0, stream>>>(feat, meta, ent, out, K);
}